// Round 1
// baseline (192.970 us; speedup 1.0000x reference)
//
#include <hip/hip_runtime.h>

typedef unsigned short u16;
typedef unsigned int u32;
typedef unsigned long long u64;

typedef __bf16 bf16x8 __attribute__((ext_vector_type(8)));
typedef float f32x4 __attribute__((ext_vector_type(4)));

#define LOG2E 1.44269504088896340736f

__device__ __forceinline__ float b2f(u16 u) {
    u32 x = ((u32)u) << 16;
    return __builtin_bit_cast(float, x);
}
__device__ __forceinline__ u16 f2b(float f) {
    u32 u = __builtin_bit_cast(u32, f);
    u32 r = (u + 0x7fffu + ((u >> 16) & 1u)) >> 16;
    return (u16)r;
}
__device__ __forceinline__ float ld(const void* p, int i, bool bf) {
    return bf ? b2f(((const u16*)p)[i]) : ((const float*)p)[i];
}
template<bool BF>
__device__ __forceinline__ float ldt(const void* p, int i) {
    return BF ? b2f(((const u16*)p)[i]) : ((const float*)p)[i];
}
__device__ __forceinline__ bool detect_bf16(const void* masks) {
    return ((const u16*)masks)[0] != 0;
}
__device__ __forceinline__ f32x4 mfma16(bf16x8 a, bf16x8 b, f32x4 c) {
    return __builtin_amdgcn_mfma_f32_16x16x32_bf16(a, b, c, 0, 0, 0);
}

// ---------------- device-global scratch ----------------
__device__ __attribute__((aligned(256))) u32  g_adjm[16384 * 16];   // bitmask
__device__ __attribute__((aligned(256))) u16  g_BT1[512 * 128];     // W_heads^T [h*64+o][k]
__device__ __attribute__((aligned(256))) u16  g_BT2[128 * 512];     // W_out^T
__device__ __attribute__((aligned(256))) u16  g_Xc[32 * 512 * 128]; // bf16 graph_inf (f32 case)
__device__ __attribute__((aligned(256))) u16  g_xb[16384 * 512];    // concat ELU output
__device__ __attribute__((aligned(256))) u16  g_Wh2[16384 * 128];   // out-layer features
__device__ __attribute__((aligned(256))) float g_s1b[16384];        // x log2e
__device__ __attribute__((aligned(256))) float g_s2b[16384];

// ---------------------------------------------------------------------------
// PREP: adj -> bitmask (ballot-free, 8-deep MLP); weight transposes; Xc cast.
// [R13: dropped fc1T/fc2T/fc3T transposes -- MLP now reads original layouts]
// ---------------------------------------------------------------------------
__global__ __launch_bounds__(256) void prep_kernel(
    const int* __restrict__ adj, const void* __restrict__ Whd,
    const void* __restrict__ Wo, const void* __restrict__ Xin,
    const void* __restrict__ masks)
{
    const bool bf = detect_bf16(masks);
    const int blk = blockIdx.x;
    const int tid = threadIdx.x;
    if (blk < 1024) {
        int id = blk * 256 + tid;
        int row = id >> 4, w = id & 15;
        const int4* p = (const int4*)(adj + row * 512 + w * 32);
        int4 v[8];
        #pragma unroll
        for (int s = 0; s < 8; ++s) v[s] = p[s];
        u32 word = 0;
        #pragma unroll
        for (int s = 0; s < 8; ++s) {
            u32 nib = (v[s].x > 0 ? 1u : 0u) | (v[s].y > 0 ? 2u : 0u) |
                      (v[s].z > 0 ? 4u : 0u) | (v[s].w > 0 ? 8u : 0u);
            word |= nib << (4 * s);
        }
        g_adjm[id] = word;
    } else if (blk < 1028) {
        int base = (blk - 1024) * 16384;
        for (int e = base + tid; e < base + 16384; e += 256) {
            int n = e >> 7, k = e & 127;           // BT1[n][k] = W_heads[h][k][o]
            g_BT1[e] = f2b(ld(Whd, (n >> 6) * 8192 + k * 64 + (n & 63), bf));
        }
    } else if (blk < 1032) {
        int base = (blk - 1028) * 16384;
        for (int e = base + tid; e < base + 16384; e += 256) {
            int n = e >> 9, k = e & 511;           // BT2[n][k] = W_out[k][n]
            g_BT2[e] = f2b(ld(Wo, k * 128 + n, bf));
        }
    } else {
        if (!bf) {
            int base = (blk - 1032) * 8192;
            for (int e = base + tid; e < base + 8192; e += 256)
                g_Xc[e] = f2b(((const float*)Xin)[e]);
        }
    }
}

// ---------------------------------------------------------------------------
// GAT1 v2 (fused gemm1 + scores + attention): 256 blocks x 1024 threads
// (16 waves = 4 waves/SIMD). b = blockIdx&31, h = blockIdx>>5 so all 8
// h-blocks of a batch share one XCD (XCD = blockIdx%8) -> Xc/adj fetched
// once per XCD L2. Phase 1: Wh = BT1_h @ Xc[b]^T chunk-wise into LDS
// (register-prefetched staging); s1/s2 fp32 partials in LDS.
// Phase 2: attention, each wave owns 32 rows (2 groups).
// [R11 config -- measured best 185.8 us; R12's split regressed to 192.0]
// ---------------------------------------------------------------------------
__global__ __launch_bounds__(1024, 1) void gat1_kernel(
    const void* __restrict__ Xin, const void* __restrict__ a_heads,
    const void* __restrict__ masks)
{
    __shared__ __attribute__((aligned(16))) u16 WhL[64 * 520];   // [o][node]
    __shared__ __attribute__((aligned(16))) u16 As[64 * 136];    // BT1 h-slice
    __shared__ __attribute__((aligned(16))) u16 XcL[128 * 136];  // node chunk
    __shared__ float s1p[4][512];
    __shared__ float s2p[4][512];
    __shared__ float E2s[512];
    __shared__ float E2ps[512];

    const bool bf = detect_bf16(masks);
    const int tid = threadIdx.x;
    const int w = tid >> 6, lane = tid & 63;
    const int c = lane & 15, q = lane >> 4;
    const int b = blockIdx.x & 31;
    const int h = blockIdx.x >> 5;

    const u16* Bsrc = bf ? (const u16*)Xin : g_Xc;   // [b*512+n][128]

    // stage As: BT1 rows h*64+r (64 rows x 128 k); 1024 thr -> 1 uint4 each
    {
        int r = tid >> 4, seg = (tid & 15) * 8;
        *(uint4*)&As[r * 136 + seg] = *(const uint4*)(g_BT1 + (h * 64 + r) * 128 + seg);
    }

    // Phase 1: 4 node-chunks of 128; wave = (wm feature-tile, wn node-32-slice)
    const int wm = w & 3, wn = w >> 2;
    float a1v[4], a2v[4];
    #pragma unroll
    for (int i = 0; i < 4; ++i) {
        int o = wm * 16 + q * 4 + i;
        a1v[i] = ld(a_heads, h * 128 + o, bf);
        a2v[i] = ld(a_heads, h * 128 + 64 + o, bf);
    }

    // register prefetch: each thread owns 16 u16 of the chunk (r = tid>>3)
    const int pr = tid >> 3, pseg = (tid & 7) * 16;
    uint4 xr0, xr1;
    {
        const u16* src = Bsrc + (b * 512 + pr) * 128 + pseg;
        xr0 = *(const uint4*)src;
        xr1 = *(const uint4*)(src + 8);
    }

    for (int chunk = 0; chunk < 4; ++chunk) {
        __syncthreads();   // XcL free (prior MFMA reads done) / As ready gate below
        *(uint4*)&XcL[pr * 136 + pseg] = xr0;
        *(uint4*)&XcL[pr * 136 + pseg + 8] = xr1;
        if (chunk < 3) {   // issue next chunk's loads now; they drain during MFMA
            const u16* src = Bsrc + (b * 512 + (chunk + 1) * 128 + pr) * 128 + pseg;
            xr0 = *(const uint4*)src;
            xr1 = *(const uint4*)(src + 8);
        }
        __syncthreads();   // XcL (and on chunk 0, As) ready
        f32x4 cacc[2] = {};
        #pragma unroll
        for (int kt = 0; kt < 4; ++kt) {
            bf16x8 af = *(const bf16x8*)&As[(wm * 16 + c) * 136 + kt * 32 + q * 8];
            #pragma unroll
            for (int nt = 0; nt < 2; ++nt) {
                bf16x8 bv = *(const bf16x8*)&XcL[(wn * 32 + nt * 16 + c) * 136 + kt * 32 + q * 8];
                cacc[nt] = mfma16(af, bv, cacc[nt]);
            }
        }
        // write WhL (bf16) + s1/s2 fp32 partials for this feature tile
        #pragma unroll
        for (int nt = 0; nt < 2; ++nt) {
            const int ncol = chunk * 128 + wn * 32 + nt * 16 + c;
            float p1 = 0.f, p2 = 0.f;
            #pragma unroll
            for (int i = 0; i < 4; ++i) {
                float v = cacc[nt][i];
                WhL[(wm * 16 + q * 4 + i) * 520 + ncol] = f2b(v);
                p1 += v * a1v[i];
                p2 += v * a2v[i];
            }
            p1 += __shfl_xor(p1, 16); p1 += __shfl_xor(p1, 32);
            p2 += __shfl_xor(p2, 16); p2 += __shfl_xor(p2, 32);
            if (lane < 16) {
                int n = chunk * 128 + wn * 32 + nt * 16 + lane;
                s1p[wm][n] = p1;
                s2p[wm][n] = p2;
            }
        }
    }
    __syncthreads();
    // E2 tables from summed partials
    {
        int j = tid & 511;
        float s2v = (s2p[0][j] + s2p[1][j] + s2p[2][j] + s2p[3][j]) * LOG2E;
        if (tid < 512) E2s[j]  = exp2f(s2v);
        else           E2ps[j] = exp2f(0.2f * s2v);
    }
    __syncthreads();

    // Phase 2: wave owns rows w*32 + g*16 + c, g in {0,1}
    const u32* adjb = g_adjm + b * 8192;
    const u32 bword = (c == 0) ? 0x3F803F80u : 0u;
    const uint4 bq = {bword, bword, bword, bword};
    const bf16x8 bone = __builtin_bit_cast(bf16x8, bq);

    float E1[2], E1p[2];
    #pragma unroll
    for (int g = 0; g < 2; ++g) {
        int r = w * 32 + g * 16 + c;
        float s1v = (s1p[0][r] + s1p[1][r] + s1p[2][r] + s1p[3][r]) * LOG2E;
        E1[g]  = exp2f(s1v);
        E1p[g] = exp2f(0.2f * s1v);
    }

    f32x4 acc[2][4] = {};
    f32x4 acc1[2] = {};
    const u16* lbase = &WhL[c * 520 + q * 8];

    for (int kc = 0; kc < 4; ++kc) {
        union { uint4 v; u32 a[4]; } wq[2];
        #pragma unroll
        for (int g = 0; g < 2; ++g)
            wq[g].v = *(const uint4*)(adjb + (w * 32 + g * 16 + c) * 16 + kc * 4);
        #pragma unroll
        for (int tl = 0; tl < 4; ++tl) {
            const int jb = kc * 128 + tl * 32 + q * 8;
            union { float4 v[2]; float f[8]; } e2r, e2pr;
            e2r.v[0]  = *(const float4*)&E2s[jb];
            e2r.v[1]  = *(const float4*)&E2s[jb + 4];
            e2pr.v[0] = *(const float4*)&E2ps[jb];
            e2pr.v[1] = *(const float4*)&E2ps[jb + 4];
            bf16x8 bfrag[4];
            #pragma unroll
            for (int nt = 0; nt < 4; ++nt)
                bfrag[nt] = *(const bf16x8*)(lbase + nt * 16 * 520 + kc * 128 + tl * 32);
            #pragma unroll
            for (int g = 0; g < 2; ++g) {
                u32 wbits = wq[g].a[tl] >> (q * 8);
                u32 pk[4];
                #pragma unroll
                for (int pi = 0; pi < 4; ++pi) {
                    float z0 = fmaxf(E1[g] * e2r.f[2 * pi],     E1p[g] * e2pr.f[2 * pi]);
                    float z1 = fmaxf(E1[g] * e2r.f[2 * pi + 1], E1p[g] * e2pr.f[2 * pi + 1]);
                    z0 = ((wbits >> (2 * pi)) & 1u) ? z0 : 0.f;
                    z1 = ((wbits >> (2 * pi + 1)) & 1u) ? z1 : 0.f;
                    pk[pi] = __builtin_amdgcn_perm(__builtin_bit_cast(u32, z1),
                                                   __builtin_bit_cast(u32, z0),
                                                   0x07060302u);
                }
                uint4 pkv = {pk[0], pk[1], pk[2], pk[3]};
                bf16x8 pv = __builtin_bit_cast(bf16x8, pkv);
                acc1[g] = mfma16(pv, bone, acc1[g]);
                #pragma unroll
                for (int nt = 0; nt < 4; ++nt)
                    acc[g][nt] = mfma16(pv, bfrag[nt], acc[g][nt]);
            }
        }
    }
    #pragma unroll
    for (int g = 0; g < 2; ++g) {
        const int R = w * 32 + g * 16;
        #pragma unroll
        for (int i = 0; i < 4; ++i) {
            float lr = __shfl(acc1[g][i], (lane & 48));
            float invr = (lr == 0.f) ? (1.f / 512.f) : (1.f / lr);
            const int row = R + q * 4 + i;
            float mk = ld(masks, b * 512 + row, bf);
            #pragma unroll
            for (int nt = 0; nt < 4; ++nt) {
                float v = acc[g][nt][i] * invr * mk;
                float o = v > 0.f ? v : (__expf(v) - 1.f);
                g_xb[(b * 512 + row) * 512 + h * 64 + nt * 16 + c] = f2b(o);
            }
        }
    }
}

// ---------------------------------------------------------------------------
// GEMM2: Wh2[16384x128] = xb @ BT2^T. BM=64, grid 256. s1b/s2b epilogue.
// ---------------------------------------------------------------------------
__global__ __launch_bounds__(256, 2) void gemm2_kernel(
    const void* __restrict__ a_out, const void* __restrict__ masks)
{
    __shared__ __attribute__((aligned(16))) u16 Asl[64 * 72];
    __shared__ __attribute__((aligned(16))) u16 Bsl[128 * 72];
    const int tid = threadIdx.x;
    const int w = tid >> 6, lane = tid & 63;
    const int c = lane & 15, q = lane >> 4;
    const int tm = blockIdx.x * 64;
    const int rowA = tid >> 2, shA = (tid & 3) * 16;
    const int rowB = tid >> 1, shB = (tid & 1) * 32;
    f32x4 acc[8] = {};
    for (int kc = 0; kc < 512; kc += 64) {
        __syncthreads();
        const u16* Ag = g_xb + (tm + rowA) * 512 + kc + shA;
        *(uint4*)&Asl[rowA * 72 + shA] = *(const uint4*)Ag;
        *(uint4*)&Asl[rowA * 72 + shA + 8] = *(const uint4*)(Ag + 8);
        const u16* Bg = g_BT2 + rowB * 512 + kc + shB;
        #pragma unroll
        for (int s = 0; s < 4; ++s)
            *(uint4*)&Bsl[rowB * 72 + shB + 8 * s] = *(const uint4*)(Bg + 8 * s);
        __syncthreads();
        #pragma unroll
        for (int kt = 0; kt < 2; ++kt) {
            bf16x8 av = *(const bf16x8*)&Asl[(w * 16 + c) * 72 + kt * 32 + q * 8];
            #pragma unroll
            for (int ct = 0; ct < 8; ++ct) {
                bf16x8 bv = *(const bf16x8*)&Bsl[(ct * 16 + c) * 72 + kt * 32 + q * 8];
                acc[ct] = mfma16(av, bv, acc[ct]);
            }
        }
    }
    const bool bf = detect_bf16(masks);
    float a1v[8], a2v[8];
    #pragma unroll
    for (int ct = 0; ct < 8; ++ct) {
        a1v[ct] = ld(a_out, ct * 16 + c, bf);
        a2v[ct] = ld(a_out, 128 + ct * 16 + c, bf);
    }
    #pragma unroll
    for (int i = 0; i < 4; ++i) {
        float p1 = 0.f, p2 = 0.f;
        #pragma unroll
        for (int ct = 0; ct < 8; ++ct) {
            p1 += acc[ct][i] * a1v[ct];
            p2 += acc[ct][i] * a2v[ct];
        }
        #pragma unroll
        for (int off = 1; off < 16; off <<= 1) {
            p1 += __shfl_xor(p1, off);
            p2 += __shfl_xor(p2, off);
        }
        if (c == 0) {
            int m = tm + w * 16 + q * 4 + i;
            g_s1b[m] = p1 * LOG2E;
            g_s2b[m] = p2 * LOG2E;
        }
    }
    #pragma unroll
    for (int ct = 0; ct < 8; ++ct)
        #pragma unroll
        for (int i = 0; i < 4; ++i) {
            int m = tm + w * 16 + q * 4 + i;
            g_Wh2[m * 128 + ct * 16 + c] = f2b(acc[ct][i]);
        }
}

// ---------------------------------------------------------------------------
// TAIL (R13): fused fin_att + fc1/fc2/fc3 + softmax, one block per batch b.
// MLP is per-batch-row independent, so each block carries its row through:
// selected-row attention -> inf[192] in LDS -> fp32 VALU dots reading the
// ORIGINAL fc*_w layouts (lane n reads col n: coalesced; weights L2-resident)
// -> block softmax -> d_out. Replaces 5 launches (fin_att, mlp1-3, softmax).
// ---------------------------------------------------------------------------
template<bool BF>
__device__ __forceinline__ void tail_body(
    const void* __restrict__ masks, const int* __restrict__ node_order,
    const void* __restrict__ workv, const void* __restrict__ subtaskv,
    const void* __restrict__ fc1w, const void* __restrict__ fc1b,
    const void* __restrict__ fc2w, const void* __restrict__ fc2b,
    const void* __restrict__ fc3w, const void* __restrict__ fc3b,
    void* __restrict__ out,
    float* att, float (*parts)[128], float* redl, float* red2,
    float* inf_s, float* h1s, float* h2s)
{
    const int b = blockIdx.x, t = threadIdx.x;
    const int lane = t & 63, wv = t >> 6;
    const int istar = node_order[b];

    // ---- selected-row attention (unchanged from fin_att) ----
    const float s1v = g_s1b[b * 512 + istar];
    const u32* arow = g_adjm + (b * 512 + istar) * 16;
    float ssum = 0.f;
    #pragma unroll
    for (int rep = 0; rep < 2; ++rep) {
        int j = t + rep * 256;
        float e = s1v + g_s2b[b * 512 + j];
        e = fmaxf(e, 0.2f * e);
        float ex = ((arow[j >> 5] >> (j & 31)) & 1u) ? exp2f(e) : 0.f;
        att[j] = ex;
        ssum += ex;
    }
    for (int off = 1; off < 64; off <<= 1) ssum += __shfl_xor(ssum, off);
    if (lane == 0) redl[wv] = ssum;
    __syncthreads();
    float tot = redl[0] + redl[1] + redl[2] + redl[3];
    bool uni = (tot == 0.f);
    float inv = uni ? (1.f / 512.f) : (1.f / tot);

    const int og = t & 15, jg = t >> 4;
    float acc[8] = {};
    const u16* base = g_Wh2 + (b * 512 + jg * 32) * 128 + og * 8;
    #pragma unroll 8
    for (int j0 = 0; j0 < 32; ++j0) {
        float wgt = uni ? 1.f : att[jg * 32 + j0];
        union { u16 u[8]; uint4 v; } z;
        z.v = *(const uint4*)(base + j0 * 128);
        #pragma unroll
        for (int i = 0; i < 8; ++i) acc[i] += wgt * b2f(z.u[i]);
    }
    #pragma unroll
    for (int i = 0; i < 8; ++i) parts[jg][og * 8 + i] = acc[i];
    __syncthreads();

    // ---- build inf[192] = {selected*inv*mk^2, work, subtask} ----
    float mk = ldt<BF>(masks, b * 512 + istar);
    if (t < 128) {
        float s = 0.f;
        #pragma unroll
        for (int jj = 0; jj < 16; ++jj) s += parts[jj][t];
        inf_s[t] = s * inv * mk * mk;
    } else if (t < 160) {
        inf_s[t] = ldt<BF>(workv, b * 32 + t - 128);
    } else if (t < 192) {
        inf_s[t] = ldt<BF>(subtaskv, b * 32 + t - 160);
    }
    __syncthreads();

    // ---- fc1: thread t owns column t (K=192) ----
    {
        float a0 = 0.f, a1 = 0.f, a2 = 0.f, a3 = 0.f;
        #pragma unroll 4
        for (int k = 0; k < 192; k += 4) {
            a0 += inf_s[k]     * ldt<BF>(fc1w, k * 256 + t);
            a1 += inf_s[k + 1] * ldt<BF>(fc1w, (k + 1) * 256 + t);
            a2 += inf_s[k + 2] * ldt<BF>(fc1w, (k + 2) * 256 + t);
            a3 += inf_s[k + 3] * ldt<BF>(fc1w, (k + 3) * 256 + t);
        }
        float v = (a0 + a1) + (a2 + a3) + ldt<BF>(fc1b, t);
        h1s[t] = fmaxf(v, 0.f);
    }
    __syncthreads();

    // ---- fc2: thread t owns column t (K=256) ----
    {
        float a0 = 0.f, a1 = 0.f, a2 = 0.f, a3 = 0.f;
        #pragma unroll 4
        for (int k = 0; k < 256; k += 4) {
            a0 += h1s[k]     * ldt<BF>(fc2w, k * 256 + t);
            a1 += h1s[k + 1] * ldt<BF>(fc2w, (k + 1) * 256 + t);
            a2 += h1s[k + 2] * ldt<BF>(fc2w, (k + 2) * 256 + t);
            a3 += h1s[k + 3] * ldt<BF>(fc2w, (k + 3) * 256 + t);
        }
        float v = (a0 + a1) + (a2 + a3) + ldt<BF>(fc2b, t);
        h2s[t] = fmaxf(v, 0.f);
    }
    __syncthreads();

    // ---- fc3: thread t owns columns t and t+256 (K=256) ----
    float lg0, lg1;
    {
        float b0 = 0.f, b1 = 0.f, c0 = 0.f, c1 = 0.f;
        #pragma unroll 4
        for (int k = 0; k < 256; k += 2) {
            float hv0 = h2s[k], hv1 = h2s[k + 1];
            b0 += hv0 * ldt<BF>(fc3w, k * 512 + t);
            c0 += hv0 * ldt<BF>(fc3w, k * 512 + 256 + t);
            b1 += hv1 * ldt<BF>(fc3w, (k + 1) * 512 + t);
            c1 += hv1 * ldt<BF>(fc3w, (k + 1) * 512 + 256 + t);
        }
        lg0 = b0 + b1 + ldt<BF>(fc3b, t);
        lg1 = c0 + c1 + ldt<BF>(fc3b, 256 + t);
    }

    // ---- block softmax over 512 (2 logits/thread) ----
    float mx = fmaxf(lg0, lg1);
    #pragma unroll
    for (int off = 1; off < 64; off <<= 1) mx = fmaxf(mx, __shfl_xor(mx, off));
    if (lane == 0) redl[wv] = mx;
    __syncthreads();
    mx = fmaxf(fmaxf(redl[0], redl[1]), fmaxf(redl[2], redl[3]));
    float e0 = __expf(lg0 - mx), e1 = __expf(lg1 - mx);
    float s = e0 + e1;
    #pragma unroll
    for (int off = 1; off < 64; off <<= 1) s += __shfl_xor(s, off);
    if (lane == 0) red2[wv] = s;
    __syncthreads();
    float invs = 1.f / (red2[0] + red2[1] + red2[2] + red2[3]);
    if (BF) {
        u16* o = (u16*)out + b * 512;
        o[t]       = f2b(e0 * invs);
        o[256 + t] = f2b(e1 * invs);
    } else {
        float* o = (float*)out + b * 512;
        o[t]       = e0 * invs;
        o[256 + t] = e1 * invs;
    }
}

__global__ __launch_bounds__(256) void tail_kernel(
    const void* __restrict__ masks, const int* __restrict__ node_order,
    const void* __restrict__ workv, const void* __restrict__ subtaskv,
    const void* __restrict__ fc1w, const void* __restrict__ fc1b,
    const void* __restrict__ fc2w, const void* __restrict__ fc2b,
    const void* __restrict__ fc3w, const void* __restrict__ fc3b,
    void* __restrict__ out)
{
    __shared__ float att[512];
    __shared__ float parts[16][128];
    __shared__ float redl[4];
    __shared__ float red2[4];
    __shared__ float inf_s[192];
    __shared__ float h1s[256];
    __shared__ float h2s[256];
    if (detect_bf16(masks))
        tail_body<true>(masks, node_order, workv, subtaskv, fc1w, fc1b, fc2w, fc2b,
                        fc3w, fc3b, out, att, parts, redl, red2, inf_s, h1s, h2s);
    else
        tail_body<false>(masks, node_order, workv, subtaskv, fc1w, fc1b, fc2w, fc2b,
                         fc3w, fc3b, out, att, parts, redl, red2, inf_s, h1s, h2s);
}

// ---------------------------------------------------------------------------
extern "C" void kernel_launch(void* const* d_in, const int* in_sizes, int n_in,
                              void* d_out, int out_size, void* d_ws, size_t ws_size,
                              hipStream_t stream)
{
    const void* graph_inf    = d_in[0];
    const int*  graph_matrix = (const int*)d_in[1];
    const void* masks        = d_in[2];
    const int*  node_order   = (const int*)d_in[3];
    const void* work         = d_in[4];
    const void* subtask      = d_in[5];
    const void* W_heads      = d_in[6];
    const void* a_heads      = d_in[7];
    const void* W_out        = d_in[8];
    const void* a_out        = d_in[9];
    const void* fc1w         = d_in[10];
    const void* fc1b         = d_in[11];
    const void* fc2w         = d_in[12];
    const void* fc2b         = d_in[13];
    const void* fc3w         = d_in[14];
    const void* fc3b         = d_in[15];

    prep_kernel<<<dim3(1288), dim3(256), 0, stream>>>(graph_matrix, W_heads, W_out,
                                                      graph_inf, masks);
    gat1_kernel<<<dim3(256), dim3(1024), 0, stream>>>(graph_inf, a_heads, masks);
    gemm2_kernel<<<dim3(256), dim3(256), 0, stream>>>(a_out, masks);
    tail_kernel<<<dim3(32), dim3(256), 0, stream>>>(masks, node_order, work, subtask,
                                                    fc1w, fc1b, fc2w, fc2b, fc3w, fc3b,
                                                    d_out);
}